// Round 1
// baseline (290.532 us; speedup 1.0000x reference)
//
#include <hip/hip_runtime.h>
#include <cstdint>
#include <cstddef>

#define D 128
#define P_DROP 0.1f
#define INV_KEEP (1.0f / 0.9f)
#define BN_EPS 1e-5f

// ---------------- init: zero hist/cursor/bn accumulators ----------------
__global__ void k_init(int* __restrict__ hist, int* __restrict__ cursor,
                       float* __restrict__ bnacc, int N) {
    int i = blockIdx.x * blockDim.x + threadIdx.x;
    if (i < N) { hist[i] = 0; cursor[i] = 0; }
    if (i < 256) bnacc[i] = 0.f;
}

// ---------------- histogram of dst (in-degree, excl. self loop) ----------------
__global__ void k_hist(const int* __restrict__ dst, int* __restrict__ hist, int E) {
    int i = blockIdx.x * blockDim.x + threadIdx.x;
    if (i < E) atomicAdd(&hist[dst[i]], 1);
}

// ---------------- 2-level exclusive scan ----------------
__global__ void k_scanA(const int* __restrict__ hist, int* __restrict__ tmp,
                        int* __restrict__ blocksum, int N) {
    __shared__ int sd[256];
    int tid = threadIdx.x;
    int i = blockIdx.x * 256 + tid;
    sd[tid] = (i < N) ? hist[i] : 0;
    __syncthreads();
    for (int o = 1; o < 256; o <<= 1) {
        int t = (tid >= o) ? sd[tid - o] : 0;
        __syncthreads();
        sd[tid] += t;
        __syncthreads();
    }
    tmp[i] = sd[tid];                       // inclusive within block
    if (tid == 255) blocksum[blockIdx.x] = sd[255];
}

__global__ void k_scanB(const int* __restrict__ blocksum, int* __restrict__ blockoff,
                        int NBLK) {
    __shared__ int sd[256];
    int tid = threadIdx.x;
    int v = (tid < NBLK) ? blocksum[tid] : 0;
    sd[tid] = v;
    __syncthreads();
    for (int o = 1; o < 256; o <<= 1) {
        int t = (tid >= o) ? sd[tid - o] : 0;
        __syncthreads();
        sd[tid] += t;
        __syncthreads();
    }
    if (tid < NBLK) blockoff[tid] = sd[tid] - v;   // exclusive
}

__global__ void k_scanC(const int* __restrict__ tmp, const int* __restrict__ blockoff,
                        int* __restrict__ off, int N) {
    int i = blockIdx.x * 256 + threadIdx.x;
    if (i < N) off[i + 1] = tmp[i] + blockoff[blockIdx.x];
    if (i == 0) off[0] = 0;
}

// ---------------- CSR placement ----------------
__global__ void k_place(const int* __restrict__ src, const int* __restrict__ dst,
                        const int* __restrict__ off, int* __restrict__ cursor,
                        int* __restrict__ ebuf, int E) {
    int i = blockIdx.x * blockDim.x + threadIdx.x;
    if (i < E) {
        int d = dst[i];
        int p = atomicAdd(&cursor[d], 1);
        ebuf[off[d] + p] = src[i];
    }
}

// ---------------- GEMM xw' = (x @ W) * rsqrt(deg) ----------------
// block: 256 thr, tile 64 rows x 128 cols, thread = 4 rows x 8 cols
__global__ __launch_bounds__(256) void k_gemm(
    const float* __restrict__ x, const float* __restrict__ w,
    const int* __restrict__ hist, float* __restrict__ xwp,
    float* __restrict__ dinv, int N) {
    __shared__ float wl[32][D];     // 16 KB
    __shared__ float xl[32][68];    // 8.5 KB, transposed x tile (pad 68 keeps f4 align)
    int tid = threadIdx.x;
    int tx = tid & 15, ty = tid >> 4;
    int row0 = blockIdx.x * 64;
    float acc[4][8];
#pragma unroll
    for (int r = 0; r < 4; ++r)
#pragma unroll
        for (int c = 0; c < 8; ++c) acc[r][c] = 0.f;

    for (int k0 = 0; k0 < D; k0 += 32) {
#pragma unroll
        for (int i = 0; i < 4; ++i) {                   // W chunk 32x128
            int f = tid + i * 256;
            int kk = f >> 5, cc = (f & 31) << 2;
            *(float4*)&wl[kk][cc] = *(const float4*)&w[(size_t)(k0 + kk) * D + cc];
        }
#pragma unroll
        for (int i = 0; i < 2; ++i) {                   // x chunk 64 rows x 32 k, transposed
            int f = tid + i * 256;
            int r = f >> 3, kk = (f & 7) << 2;
            int row = row0 + r;
            float4 v = (row < N) ? *(const float4*)&x[(size_t)row * D + k0 + kk]
                                 : make_float4(0.f, 0.f, 0.f, 0.f);
            xl[kk + 0][r] = v.x; xl[kk + 1][r] = v.y;
            xl[kk + 2][r] = v.z; xl[kk + 3][r] = v.w;
        }
        __syncthreads();
#pragma unroll
        for (int k = 0; k < 32; ++k) {
            float4 xa = *(float4*)&xl[k][ty * 4];
            float4 w0 = *(float4*)&wl[k][tx * 8];
            float4 w1 = *(float4*)&wl[k][tx * 8 + 4];
            float xr[4] = {xa.x, xa.y, xa.z, xa.w};
#pragma unroll
            for (int r = 0; r < 4; ++r) {
                acc[r][0] = fmaf(xr[r], w0.x, acc[r][0]);
                acc[r][1] = fmaf(xr[r], w0.y, acc[r][1]);
                acc[r][2] = fmaf(xr[r], w0.z, acc[r][2]);
                acc[r][3] = fmaf(xr[r], w0.w, acc[r][3]);
                acc[r][4] = fmaf(xr[r], w1.x, acc[r][4]);
                acc[r][5] = fmaf(xr[r], w1.y, acc[r][5]);
                acc[r][6] = fmaf(xr[r], w1.z, acc[r][6]);
                acc[r][7] = fmaf(xr[r], w1.w, acc[r][7]);
            }
        }
        __syncthreads();
    }
#pragma unroll
    for (int r = 0; r < 4; ++r) {
        int row = row0 + ty * 4 + r;
        if (row < N) {
            float dv = rsqrtf((float)(hist[row] + 1));  // deg includes self loop
            if (tx == 0) dinv[row] = dv;
            float4 o0 = make_float4(acc[r][0] * dv, acc[r][1] * dv,
                                    acc[r][2] * dv, acc[r][3] * dv);
            float4 o1 = make_float4(acc[r][4] * dv, acc[r][5] * dv,
                                    acc[r][6] * dv, acc[r][7] * dv);
            *(float4*)&xwp[(size_t)row * D + tx * 8] = o0;
            *(float4*)&xwp[(size_t)row * D + tx * 8 + 4] = o1;
        }
    }
}

// ---------------- gather-aggregate + bias + ReLU + BN partial sums ----------------
// one wave per node; lane holds cols {2l, 2l+1}
__global__ __launch_bounds__(256) void k_aggregate(
    const float* __restrict__ xwp, const float* __restrict__ dinv,
    const int* __restrict__ off, const int* __restrict__ ebuf,
    const float* __restrict__ bias, float* __restrict__ y,
    float* __restrict__ bnacc, int N, int NW) {
    int tid = threadIdx.x;
    int lane = tid & 63;
    int wv = tid >> 6;
    int wglob = blockIdx.x * 4 + wv;
    float2 b2 = *(const float2*)&bias[lane * 2];
    float ps0 = 0.f, ps1 = 0.f, pq0 = 0.f, pq1 = 0.f;

    for (int node = wglob; node < N; node += NW) {
        int s0 = __builtin_amdgcn_readfirstlane(off[node]);
        int s1 = __builtin_amdgcn_readfirstlane(off[node + 1]);
        const float* base = xwp + (size_t)node * D + lane * 2;
        float ax = base[0], ay = base[1];            // self-loop term (already *dinv[node])
        int e = s0;
        for (; e + 2 <= s1; e += 2) {                // unroll 2 for load ILP
            int sA = ebuf[e], sB = ebuf[e + 1];
            float2 vA = *(const float2*)(xwp + (size_t)sA * D + lane * 2);
            float2 vB = *(const float2*)(xwp + (size_t)sB * D + lane * 2);
            ax += vA.x + vB.x;
            ay += vA.y + vB.y;
        }
        if (e < s1) {
            int sA = ebuf[e];
            float2 vA = *(const float2*)(xwp + (size_t)sA * D + lane * 2);
            ax += vA.x; ay += vA.y;
        }
        float dv = dinv[node];
        float y0 = fmaxf(fmaf(ax, dv, b2.x), 0.f);
        float y1 = fmaxf(fmaf(ay, dv, b2.y), 0.f);
        *(float2*)(y + (size_t)node * D + lane * 2) = make_float2(y0, y1);
        ps0 += y0; ps1 += y1;
        pq0 += y0 * y0; pq1 += y1 * y1;
    }

    __shared__ float red_s[4][128];
    __shared__ float red_q[4][128];
    red_s[wv][2 * lane] = ps0; red_s[wv][2 * lane + 1] = ps1;
    red_q[wv][2 * lane] = pq0; red_q[wv][2 * lane + 1] = pq1;
    __syncthreads();
    if (tid < 128) {
        float s = red_s[0][tid] + red_s[1][tid] + red_s[2][tid] + red_s[3][tid];
        atomicAdd(&bnacc[tid], s);
    } else {
        int c = tid - 128;
        float q = red_q[0][c] + red_q[1][c] + red_q[2][c] + red_q[3][c];
        atomicAdd(&bnacc[128 + c], q);
    }
}

// ---------------- BN finalize: per-column scale/shift ----------------
__global__ void k_bnfinal(const float* __restrict__ bnacc, const float* __restrict__ gamma,
                          const float* __restrict__ beta, float* __restrict__ scsh, int N) {
    int c = threadIdx.x;
    if (c < 128) {
        float invN = 1.0f / (float)N;
        float mean = bnacc[c] * invN;
        float var = bnacc[128 + c] * invN - mean * mean;
        var = fmaxf(var, 0.f);
        float sc = gamma[c] * rsqrtf(var + BN_EPS);
        scsh[c] = sc;
        scsh[128 + c] = beta[c] - mean * sc;
    }
}

// ---------------- normalize + dropout, in place on d_out ----------------
__global__ __launch_bounds__(256) void k_finalize(
    float* __restrict__ out, const float* __restrict__ u,
    const float* __restrict__ scsh, int total4) {
    int i = blockIdx.x * 256 + threadIdx.x;
    if (i >= total4) return;
    float4 v = ((const float4*)out)[i];
    float4 uu = ((const float4*)u)[i];
    int c = (i & 31) * 4;                 // column of first element (D/4 = 32 f4 per row)
    float s0 = scsh[c], s1 = scsh[c + 1], s2 = scsh[c + 2], s3 = scsh[c + 3];
    float h0 = scsh[128 + c], h1 = scsh[128 + c + 1];
    float h2 = scsh[128 + c + 2], h3 = scsh[128 + c + 3];
    v.x = fmaf(v.x, s0, h0) * (uu.x > P_DROP ? INV_KEEP : 0.f);
    v.y = fmaf(v.y, s1, h1) * (uu.y > P_DROP ? INV_KEEP : 0.f);
    v.z = fmaf(v.z, s2, h2) * (uu.z > P_DROP ? INV_KEEP : 0.f);
    v.w = fmaf(v.w, s3, h3) * (uu.w > P_DROP ? INV_KEEP : 0.f);
    ((float4*)out)[i] = v;
}

extern "C" void kernel_launch(void* const* d_in, const int* in_sizes, int n_in,
                              void* d_out, int out_size, void* d_ws, size_t ws_size,
                              hipStream_t stream) {
    const float* x      = (const float*)d_in[0];
    const float* weight = (const float*)d_in[1];
    const float* bias   = (const float*)d_in[2];
    const float* gamma  = (const float*)d_in[3];
    const float* beta   = (const float*)d_in[4];
    const float* du     = (const float*)d_in[5];
    const int*   eidx   = (const int*)d_in[6];
    float* out = (float*)d_out;

    const int N = in_sizes[0] / D;      // 50000
    const int E = in_sizes[6] / 2;      // 600000
    const int* esrc = eidx;
    const int* edst = eidx + E;

    char* p = (char*)d_ws;
    auto alloc = [&](size_t bytes) {
        char* q = p;
        p += (bytes + 255) & ~(size_t)255;
        return q;
    };
    float* xwp      = (float*)alloc((size_t)N * D * sizeof(float));
    int*   hist     = (int*)alloc((size_t)N * sizeof(int));
    int*   cursor   = (int*)alloc((size_t)N * sizeof(int));
    int*   off      = (int*)alloc((size_t)(N + 1) * sizeof(int));
    const int NBLK = (N + 255) / 256;   // 196 (<=256 required by scanB)
    int*   tmp      = (int*)alloc((size_t)NBLK * 256 * sizeof(int));
    int*   blocksum = (int*)alloc((size_t)NBLK * sizeof(int));
    int*   blockoff = (int*)alloc((size_t)NBLK * sizeof(int));
    int*   ebuf     = (int*)alloc((size_t)E * sizeof(int));
    float* dinv     = (float*)alloc((size_t)N * sizeof(float));
    float* bnacc    = (float*)alloc(256 * sizeof(float));
    float* scsh     = (float*)alloc(256 * sizeof(float));

    const int EB = (E + 255) / 256;
    hipLaunchKernelGGL(k_init, dim3(NBLK), dim3(256), 0, stream, hist, cursor, bnacc, N);
    hipLaunchKernelGGL(k_hist, dim3(EB), dim3(256), 0, stream, edst, hist, E);
    hipLaunchKernelGGL(k_scanA, dim3(NBLK), dim3(256), 0, stream, hist, tmp, blocksum, N);
    hipLaunchKernelGGL(k_scanB, dim3(1), dim3(256), 0, stream, blocksum, blockoff, NBLK);
    hipLaunchKernelGGL(k_scanC, dim3(NBLK), dim3(256), 0, stream, tmp, blockoff, off, N);
    hipLaunchKernelGGL(k_place, dim3(EB), dim3(256), 0, stream, esrc, edst, off, cursor, ebuf, E);
    hipLaunchKernelGGL(k_gemm, dim3((N + 63) / 64), dim3(256), 0, stream,
                       x, weight, hist, xwp, dinv, N);
    const int AGG_BLOCKS = 2048;
    hipLaunchKernelGGL(k_aggregate, dim3(AGG_BLOCKS), dim3(256), 0, stream,
                       xwp, dinv, off, ebuf, bias, out, bnacc, N, AGG_BLOCKS * 4);
    hipLaunchKernelGGL(k_bnfinal, dim3(1), dim3(128), 0, stream, bnacc, gamma, beta, scsh, N);
    const int total4 = N * (D / 4);
    hipLaunchKernelGGL(k_finalize, dim3((total4 + 255) / 256), dim3(256), 0, stream,
                       out, du, scsh, total4);
}